// Round 7
// baseline (421.443 us; speedup 1.0000x reference)
//
#include <hip/hip_runtime.h>

typedef unsigned short ushort_t;
typedef __attribute__((ext_vector_type(8))) short short8;
typedef __attribute__((ext_vector_type(8))) __bf16 bf16x8;
typedef __attribute__((ext_vector_type(4))) float floatx4;

#define NN 96
#define DD 64
#define BSZ 16
#define TSTEP 12
#define JSPLIT 8
#define JPW 12   /* 96 / JSPLIT */
#define ITILES 6
#define NTILE (BSZ*ITILES)   /* 96 tiles per step */

// workspace offsets (bytes)
#define OFF_HALL  0u           /* 13 slots * 393216 = 5111808 */
#define OFF_E     5111808u     /* 73728 */
#define OFF_SG    5185536u     /* 12 slots * 393216 = 4718592 */
#define OFF_RG    9904128u     /* 4718592 */
#define OFF_PART  14622720u    /* 8*393216 = 3145728 */
#define OFF_WSWZ  17768448u    /* 73728 */
#define OFF_CNT   17842176u    /* 12*96*4 = 4608 */
#define OFF_FLAG  17846784u    /* 12*96*4 = 4608 */
#define HSLOT     98304        /* floats per hidden/S/R slot */

union fragU  { short8 s; bf16x8 b; };
union packU  { floatx4 f; unsigned long long u[2]; };

static __device__ __forceinline__ short f2bf(float f){
    union { float f; unsigned u; } v; v.f = f;
    unsigned u = v.u;
    u += 0x7fffu + ((u >> 16) & 1u);   // RNE
    return (short)(u >> 16);
}
// inputs provably bounded (|h|<=1, 0.05-scale weights) -> no clamps needed
static __device__ __forceinline__ float fast_tanh(float x){
    float p = __expf(2.f * x);
    return (p - 1.f) * __builtin_amdgcn_rcpf(p + 1.f);
}
static __device__ __forceinline__ float fast_sigmoid(float x){
    float p = __expf(-x);
    return __builtin_amdgcn_rcpf(1.f + p);
}
static __device__ __forceinline__ void zero4(floatx4* a){
    floatx4 z = {0.f,0.f,0.f,0.f};
    a[0]=z; a[1]=z; a[2]=z; a[3]=z;
}
// agent-scope (device-coherent, L3) 16B load/store — R6-validated handoff primitive
static __device__ __forceinline__ floatx4 aload4(const float* p){
    const unsigned long long* s = (const unsigned long long*)p;
    packU pk;
    pk.u[0] = __hip_atomic_load(s,     __ATOMIC_RELAXED, __HIP_MEMORY_SCOPE_AGENT);
    pk.u[1] = __hip_atomic_load(s + 1, __ATOMIC_RELAXED, __HIP_MEMORY_SCOPE_AGENT);
    return pk.f;
}
static __device__ __forceinline__ void astore4(float* p, floatx4 v){
    unsigned long long* d = (unsigned long long*)p;
    packU pk; pk.f = v;
    __hip_atomic_store(d,     pk.u[0], __ATOMIC_RELAXED, __HIP_MEMORY_SCOPE_AGENT);
    __hip_atomic_store(d + 1, pk.u[1], __ATOMIC_RELAXED, __HIP_MEMORY_SCOPE_AGENT);
}
// read A-fragments (16x64, row m = lane&15, k = quad*8+jj) from LDS tile stride 68
static __device__ __forceinline__ void buildA(const float* sM, int col, int quad, short8& a0, short8& a1){
    floatx4 f0 = *(const floatx4*)&sM[col*68 + quad*8];
    floatx4 f1 = *(const floatx4*)&sM[col*68 + quad*8 + 4];
    floatx4 f2 = *(const floatx4*)&sM[col*68 + 32 + quad*8];
    floatx4 f3 = *(const floatx4*)&sM[col*68 + 32 + quad*8 + 4];
    fragU u0, u1;
    #pragma unroll
    for (int jj = 0; jj < 4; jj++){
        u0.b[jj]   = (__bf16)f0[jj];
        u0.b[4+jj] = (__bf16)f1[jj];
        u1.b[jj]   = (__bf16)f2[jj];
        u1.b[4+jj] = (__bf16)f3[jj];
    }
    a0 = u0.s; a1 = u1.s;
}
// 16x64 = (16x64) @ (64x64), B pre-swizzled fragment-major
static __device__ __forceinline__ void mm16(short8 a0, short8 a1, const short8* wzm, int l, floatx4* acc){
    #pragma unroll
    for (int nt = 0; nt < 4; nt++){
        short8 b0 = wzm[nt*64 + l];
        short8 b1 = wzm[(4 + nt)*64 + l];
        acc[nt] = __builtin_amdgcn_mfma_f32_16x16x32_bf16(a0, b0, acc[nt], 0, 0, 0);
        acc[nt] = __builtin_amdgcn_mfma_f32_16x16x32_bf16(a1, b1, acc[nt], 0, 0, 0);
    }
}
// mm16 with preloaded B fragments
static __device__ __forceinline__ void mm16r(short8 a0, short8 a1, const short8* f, floatx4* acc){
    #pragma unroll
    for (int nt = 0; nt < 4; nt++){
        acc[nt] = __builtin_amdgcn_mfma_f32_16x16x32_bf16(a0, f[nt],     acc[nt], 0, 0, 0);
        acc[nt] = __builtin_amdgcn_mfma_f32_16x16x32_bf16(a1, f[4 + nt], acc[nt], 0, 0, 0);
    }
}

// ---------------------------------------------------------------------------
// init: zero hall slot0 + cnt + flags, compute E_*, pre-swizzle weights.
// grid 312 = 96(zero) + 72(E) + 144(swizzle), 256 threads.
// ---------------------------------------------------------------------------
__global__ __launch_bounds__(256) void k_init(
    const float* __restrict__ emb, const float* __restrict__ Wmsg1,
    const float* __restrict__ Wmsg2,
    const float* __restrict__ Whr, const float* __restrict__ Whi, const float* __restrict__ Whh,
    const float* __restrict__ Wir, const float* __restrict__ bir,
    const float* __restrict__ Wii, const float* __restrict__ bii,
    const float* __restrict__ Win, const float* __restrict__ bin,
    const float* __restrict__ Wo1, const float* __restrict__ Wo2, const float* __restrict__ Wo3,
    float* __restrict__ hz, int* __restrict__ cntflag,
    float* __restrict__ Ef, ushort_t* __restrict__ wswz)
{
    int wg = blockIdx.x, tid = threadIdx.x;
    if (wg < 96) {                        // zero hall slot0 (24576 float4)
        floatx4 z = {0.f,0.f,0.f,0.f};
        ((floatx4*)hz)[wg*256 + tid] = z;
        if (wg < 9) {                     // zero cnt (1152) + flags (1152), contiguous
            int c = wg*256 + tid;
            if (c < 2304) cntflag[c] = 0;
        }
    } else if (wg < 168) {                // E matrices: 3 * 96 * 64
        int flat = (wg - 96)*256 + tid;
        int m = flat / 6144; int r = flat % 6144; int s = r >> 6; int d = r & 63;
        const float* W = (m==0)? Wir : (m==1)? Wii : Win;
        const float* B = (m==0)? bir : (m==1)? bii : bin;
        float acc = B[d];
        #pragma unroll 8
        for (int k = 0; k < 64; k++)
            acc += emb[s*64 + k] * W[k*64 + d];
        Ef[flat] = acc;
    } else {                              // swizzle: 9 * 4096
        int flat = (wg - 168)*256 + tid;
        int m = flat >> 12; int q = flat & 4095;
        int jj = q & 7, lane = (q >> 3) & 63, nt = (q >> 9) & 3, kc = q >> 11;
        int k = kc*32 + ((lane >> 4) << 3) + jj;
        int n = nt*16 + (lane & 15);
        const float* src; int idx = k*64 + n;
        switch (m) {
          case 0: src = Wmsg2; break;
          case 1: src = Whr;  break;
          case 2: src = Whi;  break;
          case 3: src = Whh;  break;
          case 4: src = Wmsg1; break;
          case 5: src = Wmsg1; idx = (64 + k)*64 + n; break;
          case 6: src = Wo1; break;
          case 7: src = Wo2; break;
          default: src = Wo3; break;
        }
        wswz[flat] = (ushort_t)f2bf(src[idx]);
    }
}

// ---------------------------------------------------------------------------
// persistent 12-step kernel. grid 768 = 8(js) x 16(b) x 6(it), 256 threads,
// all blocks co-resident (12 waves/CU, 30.5KB LDS, VGPR capped by bounds).
// Per step t: spin on flags {it, jt0, jt1} (set by step t-1 winners) ->
// agent-load S(t)/R(t) -> msg+aggregate (adj/Wmsg2/b2 hoisted, live in
// LDS/regs all 12 steps) -> agent-store partial -> cnt atomicAdd -> last
// block of column (b,it) runs the GRU, agent-stores h(t+1)/S(t+1)/R(t+1),
// drains (syncthreads = vmcnt 0), sets flag[t+1][b][it]. No fences anywhere.
// partial is single-buffered: its t+1 writers are gated by the flag its
// t reader (the winner) sets. S/R/h have per-step slots (no WAR).
// ---------------------------------------------------------------------------
__global__ __launch_bounds__(256, 3) void k_all(
    const float* __restrict__ adj, const float* __restrict__ b1in, const float* __restrict__ b2in,
    const int* __restrict__ skills, const float* __restrict__ Ef,
    const ushort_t* __restrict__ wswz,
    float* __restrict__ partial, float* __restrict__ Sbuf, float* __restrict__ Rbuf,
    float* __restrict__ hall, int* __restrict__ cnt, int* __restrict__ flagv)
{
    __shared__ float lds[7616];
    __shared__ int sLast;
    float* sS   = lds;           // 12*64  = 768
    float* sRB  = lds + 768;     // 16*68  = 1088
    float* sAdj = lds + 1856;    // 16*12  = 192   (persistent across steps)
    float* sAgg = lds + 2048;    // 4*1088 = 4352
    // winner-GRU regions (disjoint from sS/sRB/sAdj):
    float* sM = lds + 2048;      // 1088 (aliases sAgg[0] - safe, msg done)
    float* sG = lds + 3136;      // 3*1088 = 3264
    float* sH = lds + 6400;      // 16*64 = 1024
    float* sE = lds + 7424;      // 192

    int wg = blockIdx.x;
    int js = wg / 96; int rem = wg % 96; int b = rem / 6; int it = rem % 6;
    int tid = threadIdx.x; int w = tid >> 6; int l = tid & 63;
    int quad = l >> 4, col = l & 15;
    int j0 = js * JPW;
    int jt0 = j0 >> 4, jt1 = (j0 + JPW - 1) >> 4;

    // ---- loop-invariant state: adj tile (LDS), Wmsg2 fragments + b2 (regs) ----
    for (int q = tid; q < 16*JPW; q += 256) {
        int i = q / JPW, j = q % JPW;
        sAdj[q] = adj[(b*NN + it*16 + i)*NN + j0 + j];
    }
    const short8* wz = (const short8*)wswz;   // matrix 0 = Wmsg2
    short8 w2f[2][4];
    #pragma unroll
    for (int kc = 0; kc < 2; kc++)
      #pragma unroll
      for (int nt = 0; nt < 4; nt++)
        w2f[kc][nt] = wz[(kc*4 + nt)*64 + l];
    float b2v[4];
    #pragma unroll
    for (int nt = 0; nt < 4; nt++) b2v[nt] = b2in[nt*16 + col];

    for (int t = 0; t < TSTEP; t++) {
        // ---- obtain S(t), R(t) into LDS ----
        if (t == 0) {
            for (int q = tid; q < JPW*64; q += 256) sS[q] = 0.f;
            for (int q = tid; q < 16*64; q += 256) sRB[(q >> 6)*68 + (q & 63)] = b1in[q & 63];
        } else {
            if (tid < 3) {
                int tile = (tid == 0) ? it : (tid == 1) ? jt0 : jt1;
                const int* fp = &flagv[t*NTILE + b*ITILES + tile];
                while (__hip_atomic_load(fp, __ATOMIC_RELAXED, __HIP_MEMORY_SCOPE_AGENT) == 0)
                    __builtin_amdgcn_s_sleep(2);
            }
            __syncthreads();
            const float* St = Sbuf + (size_t)t*HSLOT;
            const float* Rt = Rbuf + (size_t)t*HSLOT;
            for (int q = tid; q < JPW*16; q += 256) {
                int row = q >> 4, c4 = (q & 15)*4;
                *(floatx4*)&sS[row*64 + c4] = aload4(&St[(b*NN + j0 + row)*64 + c4]);
            }
            for (int q = tid; q < 16*16; q += 256) {
                int row = q >> 4, c4 = (q & 15)*4;
                floatx4 r4 = aload4(&Rt[(b*NN + it*16 + row)*64 + c4]);
                floatx4 b4 = *(const floatx4*)&b1in[c4];
                *(floatx4*)&sRB[row*68 + c4] = r4 + b4;
            }
        }
        __syncthreads();

        // ---- message + aggregate ----
        float rbv[16];
        #pragma unroll
        for (int c = 0; c < 4; c++)
            *(floatx4*)&rbv[c*4] = *(const floatx4*)&sRB[col*68 + (c>>1)*32 + quad*8 + (c&1)*4];

        float agg[4][4];
        #pragma unroll
        for (int nt=0;nt<4;nt++)
          #pragma unroll
          for (int r=0;r<4;r++) agg[nt][r] = 0.f;

        for (int c = 0; c < 3; c++) {
            int jl = w*3 + c;
            float sv[16];
            #pragma unroll
            for (int cc = 0; cc < 4; cc++)
                *(floatx4*)&sv[cc*4] = *(const floatx4*)&sS[jl*64 + (cc>>1)*32 + quad*8 + (cc&1)*4];
            fragU u0, u1;
            #pragma unroll
            for (int e = 0; e < 8; e++) {
                u0.b[e] = (__bf16)fast_tanh(sv[e]   + rbv[e]);
                u1.b[e] = (__bf16)fast_tanh(sv[8+e] + rbv[8+e]);
            }
            floatx4 acc[4];
            zero4(acc);
            #pragma unroll
            for (int nt = 0; nt < 4; nt++) {
                acc[nt] = __builtin_amdgcn_mfma_f32_16x16x32_bf16(u0.s, w2f[0][nt], acc[nt], 0,0,0);
                acc[nt] = __builtin_amdgcn_mfma_f32_16x16x32_bf16(u1.s, w2f[1][nt], acc[nt], 0,0,0);
            }
            float adjv[4];
            #pragma unroll
            for (int r = 0; r < 4; r++) adjv[r] = sAdj[(quad*4 + r)*JPW + jl];
            #pragma unroll
            for (int nt = 0; nt < 4; nt++)
              #pragma unroll
              for (int r = 0; r < 4; r++)
                agg[nt][r] += adjv[r] * fast_tanh(acc[nt][r] + b2v[nt]);
        }
        #pragma unroll
        for (int nt = 0; nt < 4; nt++)
          #pragma unroll
          for (int r = 0; r < 4; r++)
            sAgg[w*1088 + (quad*4 + r)*68 + nt*16 + col] = agg[nt][r];
        __syncthreads();
        {
            int i = tid >> 4, k4 = (tid & 15)*4;
            floatx4 s0 = *(const floatx4*)&sAgg[0*1088 + i*68 + k4];
            floatx4 s1 = *(const floatx4*)&sAgg[1*1088 + i*68 + k4];
            floatx4 s2 = *(const floatx4*)&sAgg[2*1088 + i*68 + k4];
            floatx4 s3 = *(const floatx4*)&sAgg[3*1088 + i*68 + k4];
            floatx4 o = (s0 + s1) + (s2 + s3);
            o = o * (1.f/96.f);
            astore4(&partial[((js*BSZ + b)*NN + it*16 + i)*64 + k4], o);
        }
        if (t == TSTEP - 1) break;        // k_out performs the final GRU

        __syncthreads();                  // drains each wave's agent stores (vmcnt 0)
        if (tid == 0) {
            int old = atomicAdd(&cnt[t*NTILE + b*ITILES + it], 1);
            sLast = (old == JSPLIT - 1);
        }
        __syncthreads();

        if (sLast) {
            // ------------- winner GRU for tile (b, it) -------------
            const short8* wzb = (const short8*)wswz;
            short8 fG[8], fSR[8];
            if (w < 3) {
                #pragma unroll
                for (int q = 0; q < 8; q++) fG[q] = wzb[(1 + w)*512 + q*64 + l];
            }
            if (w < 2) {
                #pragma unroll
                for (int q = 0; q < 8; q++) fSR[q] = wzb[(4 + w)*512 + q*64 + l];
            }
            {   // phase A: reduce 8 partials (agent), h_old (agent), E rows
                int i = tid >> 4, k4 = (tid & 15)*4;
                floatx4 a = {0.f,0.f,0.f,0.f};
                #pragma unroll
                for (int p = 0; p < JSPLIT; p++)
                    a += aload4(&partial[((p*BSZ + b)*NN + it*16 + i)*64 + k4]);
                *(floatx4*)&sM[i*68 + k4] = a;
                *(floatx4*)&sH[i*64 + k4] =
                    aload4(&hall[(size_t)t*HSLOT + (b*NN + it*16 + i)*64 + k4]);
            }
            if (tid < 192) {
                int s = skills[b*13 + t];
                sE[tid] = Ef[(tid >> 6)*6144 + s*64 + (tid & 63)];
            }
            __syncthreads();

            // phase B: gate matmuls (wave w -> Whr, Whi, Whh)
            if (w < 3) {
                short8 a0, a1;
                buildA(sM, col, quad, a0, a1);
                floatx4 acc[4];
                zero4(acc);
                mm16r(a0, a1, fG, acc);
                #pragma unroll
                for (int nt = 0; nt < 4; nt++)
                  #pragma unroll
                  for (int r = 0; r < 4; r++)
                    sG[w*1088 + (quad*4 + r)*68 + nt*16 + col] = acc[nt][r];
            }
            __syncthreads();

            // phase C: elementwise GRU, hnew -> sM + hall[t+1] (agent)
            {
                int i = tid >> 4, k4 = (tid & 15)*4;
                float h[4];
                #pragma unroll
                for (int e = 0; e < 4; e++) {
                    int d = k4 + e;
                    float gr = fast_sigmoid(sE[d]       + sG[0*1088 + i*68 + d]);
                    float gi = fast_sigmoid(sE[64 + d]  + sG[1*1088 + i*68 + d]);
                    float nv = fast_tanh  (sE[128 + d] + gr * sG[2*1088 + i*68 + d]);
                    h[e] = (1.f - gi)*nv + gi*sH[i*64 + d];
                }
                #pragma unroll
                for (int e = 0; e < 4; e++) sM[i*68 + k4 + e] = h[e];
                floatx4 hv = { h[0], h[1], h[2], h[3] };
                astore4(&hall[(size_t)(t+1)*HSLOT + (b*NN + it*16 + i)*64 + k4], hv);
            }
            __syncthreads();

            // phase D: S (wave 0) and R (wave 1) projections -> slot t+1 (agent)
            if (w < 2) {
                short8 a0, a1;
                buildA(sM, col, quad, a0, a1);
                floatx4 acc[4];
                zero4(acc);
                mm16r(a0, a1, fSR, acc);
                float* dst = ((w == 0) ? Sbuf : Rbuf) + (size_t)(t+1)*HSLOT;
                #pragma unroll
                for (int nt = 0; nt < 4; nt++)
                  #pragma unroll
                  for (int r = 0; r < 4; r++)
                    __hip_atomic_store(&dst[(b*NN + it*16 + quad*4 + r)*64 + nt*16 + col],
                                       acc[nt][r], __ATOMIC_RELAXED, __HIP_MEMORY_SCOPE_AGENT);
            }
            __syncthreads();              // drain ALL winner waves' agent stores
            if (tid == 0)
                __hip_atomic_store(&flagv[(t+1)*NTILE + b*ITILES + it], 1,
                                   __ATOMIC_RELAXED, __HIP_MEMORY_SCOPE_AGENT);
        }
    }
}

// ---------------------------------------------------------------------------
// batched output MLP over all steps: 1152 independent 16-row tiles, 4 waves
// per block. ts==11 waves first compute h(12) from partial(t=11) + h(11).
// grid 288 x 256 threads.
// ---------------------------------------------------------------------------
__global__ __launch_bounds__(256) void k_out(
    const int* __restrict__ skills, const float* __restrict__ partial,
    const float* __restrict__ Ef, const float* __restrict__ hall,
    const ushort_t* __restrict__ wswz,
    const float* __restrict__ bo1, const float* __restrict__ bo2, const float* __restrict__ bo3,
    float* __restrict__ out)
{
    __shared__ float sT[4][16*68];
    int tid = threadIdx.x; int w = tid >> 6; int l = tid & 63;
    int quad = l >> 4, col = l & 15;
    int g = blockIdx.x*4 + w;
    int ts = g / 96; int rem = g % 96; int b = rem / 6, it = rem % 6;
    float* sm = sT[w];

    if (ts < 11) {
        const float* hsrc = hall + (size_t)(ts + 1)*HSLOT + (b*NN + it*16)*64;
        int i = l >> 2, c0 = (l & 3)*16;
        #pragma unroll
        for (int cc = 0; cc < 4; cc++)
            *(floatx4*)&sm[i*68 + c0 + cc*4] = *(const floatx4*)&hsrc[i*64 + c0 + cc*4];
    } else {
        // final GRU: reduce 8 partials into sm, gates, elementwise vs h(11)
        int i = l >> 2, c0 = (l & 3)*16;
        floatx4 a[4]; zero4(a);
        for (int p = 0; p < JSPLIT; p++) {
            const float* base = &partial[((p*BSZ + b)*NN + it*16 + i)*64 + c0];
            #pragma unroll
            for (int cc = 0; cc < 4; cc++) a[cc] += *(const floatx4*)&base[cc*4];
        }
        #pragma unroll
        for (int cc = 0; cc < 4; cc++) *(floatx4*)&sm[i*68 + c0 + cc*4] = a[cc];

        short8 a0, a1; buildA(sm, col, quad, a0, a1);
        floatx4 Ar[4], Ai[4], Ah[4];
        zero4(Ar); zero4(Ai); zero4(Ah);
        mm16(a0, a1, (const short8*)wswz + 1*512, l, Ar);
        mm16(a0, a1, (const short8*)wswz + 2*512, l, Ai);
        mm16(a0, a1, (const short8*)wswz + 3*512, l, Ah);
        int s = skills[b*13 + 11];
        const float* hp = hall + 11*(size_t)HSLOT;
        #pragma unroll
        for (int nt = 0; nt < 4; nt++) {
            int d = nt*16 + col;
            float er = Ef[0*6144 + s*64 + d];
            float ei = Ef[1*6144 + s*64 + d];
            float en = Ef[2*6144 + s*64 + d];
            #pragma unroll
            for (int r = 0; r < 4; r++) {
                int row = it*16 + quad*4 + r;
                float gr = fast_sigmoid(er + Ar[nt][r]);
                float gi = fast_sigmoid(ei + Ai[nt][r]);
                float nv = fast_tanh  (en + gr*Ah[nt][r]);
                sm[(quad*4 + r)*68 + d] = (1.f - gi)*nv + gi*hp[(b*NN + row)*64 + d];
            }
        }
    }

    float bv1[4], bv2[4], bv3[4];
    #pragma unroll
    for (int nt = 0; nt < 4; nt++) {
        bv1[nt] = bo1[nt*16 + col];
        bv2[nt] = bo2[nt*16 + col];
        bv3[nt] = bo3[nt*16 + col];
    }
    short8 a0, a1;
    floatx4 acc[4];

    buildA(sm, col, quad, a0, a1);
    zero4(acc);
    mm16(a0, a1, (const short8*)wswz + 6*512, l, acc);
    #pragma unroll
    for (int nt = 0; nt < 4; nt++)
      #pragma unroll
      for (int r = 0; r < 4; r++)
        sm[(quad*4 + r)*68 + nt*16 + col] = fmaxf(0.f, acc[nt][r] + bv1[nt]);

    buildA(sm, col, quad, a0, a1);
    zero4(acc);
    mm16(a0, a1, (const short8*)wswz + 7*512, l, acc);
    #pragma unroll
    for (int nt = 0; nt < 4; nt++)
      #pragma unroll
      for (int r = 0; r < 4; r++)
        sm[(quad*4 + r)*68 + nt*16 + col] = fmaxf(0.f, acc[nt][r] + bv2[nt]);

    buildA(sm, col, quad, a0, a1);
    zero4(acc);
    mm16(a0, a1, (const short8*)wswz + 8*512, l, acc);
    #pragma unroll
    for (int nt = 0; nt < 4; nt++)
      #pragma unroll
      for (int r = 0; r < 4; r++)
        out[((b*TSTEP + ts)*NN + it*16 + quad*4 + r)*64 + nt*16 + col] = acc[nt][r] + bv3[nt];
}

extern "C" void kernel_launch(void* const* d_in, const int* in_sizes, int n_in,
                              void* d_out, int out_size, void* d_ws, size_t ws_size,
                              hipStream_t stream) {
    const int*   skills = (const int*)d_in[0];
    const float* adj    = (const float*)d_in[1];
    const float* emb    = (const float*)d_in[2];
    const float* Wmsg1  = (const float*)d_in[3];
    const float* b1     = (const float*)d_in[4];
    const float* Wmsg2  = (const float*)d_in[5];
    const float* b2     = (const float*)d_in[6];
    const float* Whr    = (const float*)d_in[7];
    const float* Whi    = (const float*)d_in[8];
    const float* Whh    = (const float*)d_in[9];
    const float* Wir    = (const float*)d_in[10];
    const float* bir    = (const float*)d_in[11];
    const float* Wii    = (const float*)d_in[12];
    const float* bii    = (const float*)d_in[13];
    const float* Win    = (const float*)d_in[14];
    const float* bin    = (const float*)d_in[15];
    const float* Wo1    = (const float*)d_in[16];
    const float* bo1    = (const float*)d_in[17];
    const float* Wo2    = (const float*)d_in[18];
    const float* bo2    = (const float*)d_in[19];
    const float* Wo3    = (const float*)d_in[20];
    const float* bo3    = (const float*)d_in[21];

    char* ws = (char*)d_ws;
    float*    hall    = (float*)(ws + OFF_HALL);
    float*    Ef      = (float*)(ws + OFF_E);
    float*    Sbuf    = (float*)(ws + OFF_SG);
    float*    Rbuf    = (float*)(ws + OFF_RG);
    float*    partial = (float*)(ws + OFF_PART);
    ushort_t* wswz    = (ushort_t*)(ws + OFF_WSWZ);
    int*      cnt     = (int*)(ws + OFF_CNT);
    int*      flagv   = (int*)(ws + OFF_FLAG);
    float*    out     = (float*)d_out;

    k_init<<<dim3(312), dim3(256), 0, stream>>>(emb, Wmsg1, Wmsg2, Whr, Whi, Whh,
        Wir, bir, Wii, bii, Win, bin, Wo1, Wo2, Wo3, hall, cnt, Ef, wswz);

    k_all<<<dim3(JSPLIT*BSZ*ITILES), dim3(256), 0, stream>>>(
        adj, b1, b2, skills, Ef, wswz, partial, Sbuf, Rbuf, hall, cnt, flagv);

    k_out<<<dim3(288), dim3(256), 0, stream>>>(skills, partial, Ef, hall, wswz,
        bo1, bo2, bo3, out);
}

// Round 8
// 268.888 us; speedup vs baseline: 1.5674x; 1.5674x over previous
//
#include <hip/hip_runtime.h>

typedef unsigned short ushort_t;
typedef __attribute__((ext_vector_type(8))) short short8;
typedef __attribute__((ext_vector_type(8))) __bf16 bf16x8;
typedef __attribute__((ext_vector_type(4))) float floatx4;

#define NN 96
#define DD 64
#define BSZ 16
#define TSTEP 12
#define JSPLIT 8
#define JPW 12   /* 96 / JSPLIT */
#define ITILES 6
#define NTILE (BSZ*ITILES)   /* 96 tiles */

// workspace offsets (bytes)
#define OFF_HALL  0u           /* 13 slots * 393216 = 5111808 */
#define OFF_E     5111808u     /* 73728 */
#define OFF_S0    5185536u     /* 393216  even-step S (normal) */
#define OFF_R0    5578752u     /* 393216  even-step R (normal) */
#define OFF_S1    5971968u     /* 393216  odd-step S (agent)  */
#define OFF_R1    6365184u     /* 393216  odd-step R (agent)  */
#define OFF_P0    6758400u     /* 3145728 */
#define OFF_P1    9904128u     /* 3145728 */
#define OFF_WSWZ  13049856u    /* 73728 */
#define OFF_CNT   13123584u    /* 12*96*4 = 4608 */
#define OFF_FLAG  13128192u    /* 6*96*4 = 2304 */
#define HSLOT     98304        /* floats per hidden/S/R slot */

union fragU  { short8 s; bf16x8 b; };
union packU  { floatx4 f; unsigned long long u[2]; };

static __device__ __forceinline__ short f2bf(float f){
    union { float f; unsigned u; } v; v.f = f;
    unsigned u = v.u;
    u += 0x7fffu + ((u >> 16) & 1u);   // RNE
    return (short)(u >> 16);
}
// inputs provably bounded (|h|<=1, 0.05-scale weights) -> no clamps needed
static __device__ __forceinline__ float fast_tanh(float x){
    float p = __expf(2.f * x);
    return (p - 1.f) * __builtin_amdgcn_rcpf(p + 1.f);
}
static __device__ __forceinline__ float fast_sigmoid(float x){
    float p = __expf(-x);
    return __builtin_amdgcn_rcpf(1.f + p);
}
static __device__ __forceinline__ void zero4(floatx4* a){
    floatx4 z = {0.f,0.f,0.f,0.f};
    a[0]=z; a[1]=z; a[2]=z; a[3]=z;
}
// agent-scope (device-coherent, bypasses per-XCD L2) 16B load/store
static __device__ __forceinline__ floatx4 aload4(const float* p){
    const unsigned long long* s = (const unsigned long long*)p;
    packU pk;
    pk.u[0] = __hip_atomic_load(s,     __ATOMIC_RELAXED, __HIP_MEMORY_SCOPE_AGENT);
    pk.u[1] = __hip_atomic_load(s + 1, __ATOMIC_RELAXED, __HIP_MEMORY_SCOPE_AGENT);
    return pk.f;
}
static __device__ __forceinline__ void astore4(float* p, floatx4 v){
    unsigned long long* d = (unsigned long long*)p;
    packU pk; pk.f = v;
    __hip_atomic_store(d,     pk.u[0], __ATOMIC_RELAXED, __HIP_MEMORY_SCOPE_AGENT);
    __hip_atomic_store(d + 1, pk.u[1], __ATOMIC_RELAXED, __HIP_MEMORY_SCOPE_AGENT);
}
// read A-fragments (16x64, row m = lane&15, k = quad*8+jj) from LDS tile stride 68
static __device__ __forceinline__ void buildA(const float* sM, int col, int quad, short8& a0, short8& a1){
    floatx4 f0 = *(const floatx4*)&sM[col*68 + quad*8];
    floatx4 f1 = *(const floatx4*)&sM[col*68 + quad*8 + 4];
    floatx4 f2 = *(const floatx4*)&sM[col*68 + 32 + quad*8];
    floatx4 f3 = *(const floatx4*)&sM[col*68 + 32 + quad*8 + 4];
    fragU u0, u1;
    #pragma unroll
    for (int jj = 0; jj < 4; jj++){
        u0.b[jj]   = (__bf16)f0[jj];
        u0.b[4+jj] = (__bf16)f1[jj];
        u1.b[jj]   = (__bf16)f2[jj];
        u1.b[4+jj] = (__bf16)f3[jj];
    }
    a0 = u0.s; a1 = u1.s;
}
// 16x64 = (16x64) @ (64x64), B pre-swizzled fragment-major
static __device__ __forceinline__ void mm16(short8 a0, short8 a1, const short8* wzm, int l, floatx4* acc){
    #pragma unroll
    for (int nt = 0; nt < 4; nt++){
        short8 b0 = wzm[nt*64 + l];
        short8 b1 = wzm[(4 + nt)*64 + l];
        acc[nt] = __builtin_amdgcn_mfma_f32_16x16x32_bf16(a0, b0, acc[nt], 0, 0, 0);
        acc[nt] = __builtin_amdgcn_mfma_f32_16x16x32_bf16(a1, b1, acc[nt], 0, 0, 0);
    }
}
// mm16 with preloaded B fragments
static __device__ __forceinline__ void mm16r(short8 a0, short8 a1, const short8* f, floatx4* acc){
    #pragma unroll
    for (int nt = 0; nt < 4; nt++){
        acc[nt] = __builtin_amdgcn_mfma_f32_16x16x32_bf16(a0, f[nt],     acc[nt], 0, 0, 0);
        acc[nt] = __builtin_amdgcn_mfma_f32_16x16x32_bf16(a1, f[4 + nt], acc[nt], 0, 0, 0);
    }
}

// ---------------------------------------------------------------------------
// message+aggregate body (R1/R6-proven). Reads sS/sRB/sAdj (caller synced),
// one internal barrier, agent-stores the partial tile.
// ---------------------------------------------------------------------------
static __device__ __forceinline__ void msg_phase(
    const float* sS, const float* sRB, const float* sAdj, float* sAgg,
    const short8 w2f[2][4], const float b2v[4],
    int tid, int w, int quad, int col,
    float* dstP, int js, int b, int it)
{
    float rbv[16];
    #pragma unroll
    for (int c = 0; c < 4; c++)
        *(floatx4*)&rbv[c*4] = *(const floatx4*)&sRB[col*68 + (c>>1)*32 + quad*8 + (c&1)*4];

    float agg[4][4];
    #pragma unroll
    for (int nt=0;nt<4;nt++)
      #pragma unroll
      for (int r=0;r<4;r++) agg[nt][r] = 0.f;

    for (int c = 0; c < 3; c++) {
        int jl = w*3 + c;
        float sv[16];
        #pragma unroll
        for (int cc = 0; cc < 4; cc++)
            *(floatx4*)&sv[cc*4] = *(const floatx4*)&sS[jl*64 + (cc>>1)*32 + quad*8 + (cc&1)*4];
        fragU u0, u1;
        #pragma unroll
        for (int e = 0; e < 8; e++) {
            u0.b[e] = (__bf16)fast_tanh(sv[e]   + rbv[e]);
            u1.b[e] = (__bf16)fast_tanh(sv[8+e] + rbv[8+e]);
        }
        floatx4 acc[4];
        zero4(acc);
        #pragma unroll
        for (int nt = 0; nt < 4; nt++) {
            acc[nt] = __builtin_amdgcn_mfma_f32_16x16x32_bf16(u0.s, w2f[0][nt], acc[nt], 0,0,0);
            acc[nt] = __builtin_amdgcn_mfma_f32_16x16x32_bf16(u1.s, w2f[1][nt], acc[nt], 0,0,0);
        }
        float adjv[4];
        #pragma unroll
        for (int r = 0; r < 4; r++) adjv[r] = sAdj[(quad*4 + r)*JPW + jl];
        #pragma unroll
        for (int nt = 0; nt < 4; nt++)
          #pragma unroll
          for (int r = 0; r < 4; r++)
            agg[nt][r] += adjv[r] * fast_tanh(acc[nt][r] + b2v[nt]);
    }
    #pragma unroll
    for (int nt = 0; nt < 4; nt++)
      #pragma unroll
      for (int r = 0; r < 4; r++)
        sAgg[w*1088 + (quad*4 + r)*68 + nt*16 + col] = agg[nt][r];
    __syncthreads();
    {
        int i = tid >> 4, k4 = (tid & 15)*4;
        floatx4 s0 = *(const floatx4*)&sAgg[0*1088 + i*68 + k4];
        floatx4 s1 = *(const floatx4*)&sAgg[1*1088 + i*68 + k4];
        floatx4 s2 = *(const floatx4*)&sAgg[2*1088 + i*68 + k4];
        floatx4 s3 = *(const floatx4*)&sAgg[3*1088 + i*68 + k4];
        floatx4 o = (s0 + s1) + (s2 + s3);
        o = o * (1.f/96.f);
        astore4(&dstP[((js*BSZ + b)*NN + it*16 + i)*64 + k4], o);
    }
}

// ---------------------------------------------------------------------------
// winner GRU tail (R6-proven). PHASE 0 = step A (even t): hprev normal,
// h/S/R outputs agent-scope (consumed same-dispatch). PHASE 1 = step B
// (odd t): hprev agent, outputs normal (consumed next dispatch / k_out).
// ---------------------------------------------------------------------------
template<int PHASE>
static __device__ __forceinline__ void gru_tail(
    float* lds, const float* partial, const int* skills, const float* Ef,
    const ushort_t* wswz, float* hall, float* Sdst, float* Rdst,
    int b, int it, int t, int tid, int w, int l, int quad, int col)
{
    float* sM = lds + 2048;   // 1088 (aliases sAgg[0] — msg done)
    float* sG = lds + 3136;   // 3*1088
    float* sH = lds + 6400;   // 1024
    float* sE = lds + 7424;   // 192

    const short8* wzb = (const short8*)wswz;
    short8 fG[8], fSR[8];
    if (w < 3) {
        #pragma unroll
        for (int q = 0; q < 8; q++) fG[q] = wzb[(1 + w)*512 + q*64 + l];
    }
    if (w < 2) {
        #pragma unroll
        for (int q = 0; q < 8; q++) fSR[q] = wzb[(4 + w)*512 + q*64 + l];
    }
    {   // phase A: reduce 8 partials (agent), fetch h(t) + E rows
        int i = tid >> 4, k4 = (tid & 15)*4;
        floatx4 a = {0.f,0.f,0.f,0.f};
        #pragma unroll
        for (int p = 0; p < JSPLIT; p++)
            a += aload4(&partial[((p*BSZ + b)*NN + it*16 + i)*64 + k4]);
        *(floatx4*)&sM[i*68 + k4] = a;
        const float* hp = &hall[(size_t)t*HSLOT + (b*NN + it*16 + i)*64 + k4];
        *(floatx4*)&sH[i*64 + k4] = (PHASE == 0) ? *(const floatx4*)hp : aload4(hp);
    }
    if (tid < 192) {
        int s = skills[b*13 + t];
        sE[tid] = Ef[(tid >> 6)*6144 + s*64 + (tid & 63)];
    }
    __syncthreads();

    // gates: wave w -> Whr, Whi, Whh
    if (w < 3) {
        short8 a0, a1;
        buildA(sM, col, quad, a0, a1);
        floatx4 acc[4];
        zero4(acc);
        mm16r(a0, a1, fG, acc);
        #pragma unroll
        for (int nt = 0; nt < 4; nt++)
          #pragma unroll
          for (int r = 0; r < 4; r++)
            sG[w*1088 + (quad*4 + r)*68 + nt*16 + col] = acc[nt][r];
    }
    __syncthreads();

    // elementwise GRU -> sM + hall[t+1]
    {
        int i = tid >> 4, k4 = (tid & 15)*4;
        float h[4];
        #pragma unroll
        for (int e = 0; e < 4; e++) {
            int d = k4 + e;
            float gr = fast_sigmoid(sE[d]       + sG[0*1088 + i*68 + d]);
            float gi = fast_sigmoid(sE[64 + d]  + sG[1*1088 + i*68 + d]);
            float nv = fast_tanh  (sE[128 + d] + gr * sG[2*1088 + i*68 + d]);
            h[e] = (1.f - gi)*nv + gi*sH[i*64 + d];
        }
        #pragma unroll
        for (int e = 0; e < 4; e++) sM[i*68 + k4 + e] = h[e];
        floatx4 hv = { h[0], h[1], h[2], h[3] };
        float* hc = &hall[(size_t)(t+1)*HSLOT + (b*NN + it*16 + i)*64 + k4];
        if (PHASE == 0) astore4(hc, hv);
        else            *(floatx4*)hc = hv;
    }
    __syncthreads();

    // S (wave 0) / R (wave 1) projections
    if (w < 2) {
        short8 a0, a1;
        buildA(sM, col, quad, a0, a1);
        floatx4 acc[4];
        zero4(acc);
        mm16r(a0, a1, fSR, acc);
        float* dst = (w == 0) ? Sdst : Rdst;
        #pragma unroll
        for (int nt = 0; nt < 4; nt++)
          #pragma unroll
          for (int r = 0; r < 4; r++) {
            int addr = (b*NN + it*16 + quad*4 + r)*64 + nt*16 + col;
            if (PHASE == 0)
                __hip_atomic_store(&dst[addr], acc[nt][r], __ATOMIC_RELAXED, __HIP_MEMORY_SCOPE_AGENT);
            else
                dst[addr] = acc[nt][r];
          }
    }
}

// ---------------------------------------------------------------------------
// init: zero hall slot0 + cnt + flags, compute E_*, pre-swizzle weights.
// grid 312 = 96(zero) + 72(E) + 144(swizzle), 256 threads.
// ---------------------------------------------------------------------------
__global__ __launch_bounds__(256) void k_init(
    const float* __restrict__ emb, const float* __restrict__ Wmsg1,
    const float* __restrict__ Wmsg2,
    const float* __restrict__ Whr, const float* __restrict__ Whi, const float* __restrict__ Whh,
    const float* __restrict__ Wir, const float* __restrict__ bir,
    const float* __restrict__ Wii, const float* __restrict__ bii,
    const float* __restrict__ Win, const float* __restrict__ bin,
    const float* __restrict__ Wo1, const float* __restrict__ Wo2, const float* __restrict__ Wo3,
    float* __restrict__ hz, int* __restrict__ cntflag,
    float* __restrict__ Ef, ushort_t* __restrict__ wswz)
{
    int wg = blockIdx.x, tid = threadIdx.x;
    if (wg < 96) {                        // zero hall slot0 (24576 float4)
        floatx4 z = {0.f,0.f,0.f,0.f};
        ((floatx4*)hz)[wg*256 + tid] = z;
        if (wg < 7) {                     // zero cnt(1152) + flags(576), contiguous
            int c = wg*256 + tid;
            if (c < 1728) cntflag[c] = 0;
        }
    } else if (wg < 168) {                // E matrices: 3 * 96 * 64
        int flat = (wg - 96)*256 + tid;
        int m = flat / 6144; int r = flat % 6144; int s = r >> 6; int d = r & 63;
        const float* W = (m==0)? Wir : (m==1)? Wii : Win;
        const float* B = (m==0)? bir : (m==1)? bii : bin;
        float acc = B[d];
        #pragma unroll 8
        for (int k = 0; k < 64; k++)
            acc += emb[s*64 + k] * W[k*64 + d];
        Ef[flat] = acc;
    } else {                              // swizzle: 9 * 4096
        int flat = (wg - 168)*256 + tid;
        int m = flat >> 12; int q = flat & 4095;
        int jj = q & 7, lane = (q >> 3) & 63, nt = (q >> 9) & 3, kc = q >> 11;
        int k = kc*32 + ((lane >> 4) << 3) + jj;
        int n = nt*16 + (lane & 15);
        const float* src; int idx = k*64 + n;
        switch (m) {
          case 0: src = Wmsg2; break;
          case 1: src = Whr;  break;
          case 2: src = Whi;  break;
          case 3: src = Whh;  break;
          case 4: src = Wmsg1; break;
          case 5: src = Wmsg1; idx = (64 + k)*64 + n; break;
          case 6: src = Wo1; break;
          case 7: src = Wo2; break;
          default: src = Wo3; break;
        }
        wswz[flat] = (ushort_t)f2bf(src[idx]);
    }
}

// ---------------------------------------------------------------------------
// fused 2-step kernel, dispatch k handles t=2k and t2=2k+1.
// Step A: R6 path (normal S0/R0 loads, msg -> P0 agent, winner gru_tail<0>
// publishes S1/R1/h agent + flag). ONE short spin on 3 flags, agent-reload
// S1/R1, step B (msg -> P1 agent, winner gru_tail<1> -> S0/R0/h normal).
// k==5: step B is t=11, no tail (k_out does the final GRU).
// grid 768 = 8(js) x 16(b) x 6(it), 256 threads, all co-resident.
// ---------------------------------------------------------------------------
__global__ __launch_bounds__(256, 3) void k_step2(
    const float* __restrict__ adj, const float* __restrict__ b1in, const float* __restrict__ b2in,
    const int* __restrict__ skills, const float* __restrict__ Ef,
    const ushort_t* __restrict__ wswz,
    float* __restrict__ P0, float* __restrict__ P1,
    const float* __restrict__ S0r, const float* __restrict__ R0r,
    float* __restrict__ S0w, float* __restrict__ R0w,
    float* __restrict__ S1, float* __restrict__ R1,
    float* __restrict__ hall, int* __restrict__ cnt, int* __restrict__ flagv, int k)
{
    __shared__ float lds[7616];
    __shared__ int sLast;
    float* sS   = lds;           // 12*64  = 768
    float* sRB  = lds + 768;     // 16*68  = 1088
    float* sAdj = lds + 1856;    // 16*12  = 192 (persistent across both steps)
    float* sAgg = lds + 2048;    // 4*1088 = 4352

    int wg = blockIdx.x;
    int js = wg / 96; int rem = wg % 96; int b = rem / 6; int it = rem % 6;
    int tid = threadIdx.x; int w = tid >> 6; int l = tid & 63;
    int quad = l >> 4, col = l & 15;
    int j0 = js * JPW;
    int jt0 = j0 >> 4, jt1 = (j0 + JPW - 1) >> 4;
    int t = 2*k, t2 = 2*k + 1;

    // ---- prelude: adj (persistent), Wmsg2 fragments + b2 (regs) ----
    for (int q = tid; q < 16*JPW; q += 256) {
        int i = q / JPW, j = q % JPW;
        sAdj[q] = adj[(b*NN + it*16 + i)*NN + j0 + j];
    }
    const short8* wz = (const short8*)wswz;   // matrix 0 = Wmsg2
    short8 w2f[2][4];
    #pragma unroll
    for (int kc = 0; kc < 2; kc++)
      #pragma unroll
      for (int nt = 0; nt < 4; nt++)
        w2f[kc][nt] = wz[(kc*4 + nt)*64 + l];
    float b2v[4];
    #pragma unroll
    for (int nt = 0; nt < 4; nt++) b2v[nt] = b2in[nt*16 + col];

    // ---- S(t)/R(t) into LDS (normal loads; t==0 -> zeros) ----
    if (k == 0) {
        for (int q = tid; q < JPW*64; q += 256) sS[q] = 0.f;
        for (int q = tid; q < 16*64; q += 256) sRB[(q >> 6)*68 + (q & 63)] = b1in[q & 63];
    } else {
        for (int q = tid; q < JPW*16; q += 256) {
            int row = q >> 4, c4 = (q & 15)*4;
            *(floatx4*)&sS[row*64 + c4] = *(const floatx4*)&S0r[(b*NN + j0 + row)*64 + c4];
        }
        for (int q = tid; q < 16*16; q += 256) {
            int row = q >> 4, c4 = (q & 15)*4;
            floatx4 r4 = *(const floatx4*)&R0r[(b*NN + it*16 + row)*64 + c4];
            floatx4 b4 = *(const floatx4*)&b1in[c4];
            *(floatx4*)&sRB[row*68 + c4] = r4 + b4;
        }
    }
    __syncthreads();

    // ---- step A ----
    msg_phase(sS, sRB, sAdj, sAgg, w2f, b2v, tid, w, quad, col, P0, js, b, it);
    __syncthreads();                      // drain agent stores (vmcnt 0)
    if (tid == 0) {
        int old = atomicAdd(&cnt[t*NTILE + b*ITILES + it], 1);
        sLast = (old == JSPLIT - 1);
    }
    __syncthreads();
    if (sLast) {
        gru_tail<0>(lds, P0, skills, Ef, wswz, hall, S1, R1, b, it, t, tid, w, l, quad, col);
        __syncthreads();                  // drain winner agent stores
        if (tid == 0)
            __hip_atomic_store(&flagv[k*NTILE + b*ITILES + it], 1,
                               __ATOMIC_RELAXED, __HIP_MEMORY_SCOPE_AGENT);
    }

    // ---- handoff: wait for the 3 producer columns, reload S/R (agent) ----
    if (tid == 0) {
        const int* base = &flagv[k*NTILE + b*ITILES];
        const int* fp = base + it;
        while (__hip_atomic_load(fp, __ATOMIC_RELAXED, __HIP_MEMORY_SCOPE_AGENT) == 0)
            __builtin_amdgcn_s_sleep(8);
        fp = base + jt0;
        while (__hip_atomic_load(fp, __ATOMIC_RELAXED, __HIP_MEMORY_SCOPE_AGENT) == 0)
            __builtin_amdgcn_s_sleep(8);
        fp = base + jt1;
        while (__hip_atomic_load(fp, __ATOMIC_RELAXED, __HIP_MEMORY_SCOPE_AGENT) == 0)
            __builtin_amdgcn_s_sleep(8);
    }
    __syncthreads();
    for (int q = tid; q < JPW*16; q += 256) {
        int row = q >> 4, c4 = (q & 15)*4;
        *(floatx4*)&sS[row*64 + c4] = aload4(&S1[(b*NN + j0 + row)*64 + c4]);
    }
    for (int q = tid; q < 16*16; q += 256) {
        int row = q >> 4, c4 = (q & 15)*4;
        floatx4 r4 = aload4(&R1[(b*NN + it*16 + row)*64 + c4]);
        floatx4 b4 = *(const floatx4*)&b1in[c4];
        *(floatx4*)&sRB[row*68 + c4] = r4 + b4;
    }
    __syncthreads();

    // ---- step B ----
    msg_phase(sS, sRB, sAdj, sAgg, w2f, b2v, tid, w, quad, col, P1, js, b, it);
    if (k == 5) return;                   // t2 == 11: k_out does the final GRU

    __syncthreads();
    if (tid == 0) {
        int old = atomicAdd(&cnt[t2*NTILE + b*ITILES + it], 1);
        sLast = (old == JSPLIT - 1);
    }
    __syncthreads();
    if (sLast)
        gru_tail<1>(lds, P1, skills, Ef, wswz, hall, S0w, R0w, b, it, t2, tid, w, l, quad, col);
}

// ---------------------------------------------------------------------------
// batched output MLP over all steps: 1152 independent 16-row tiles, 4 waves
// per block. ts==11 waves first compute h(12) from partial(t=11) + h(11).
// grid 288 x 256 threads.
// ---------------------------------------------------------------------------
__global__ __launch_bounds__(256) void k_out(
    const int* __restrict__ skills, const float* __restrict__ partial,
    const float* __restrict__ Ef, const float* __restrict__ hall,
    const ushort_t* __restrict__ wswz,
    const float* __restrict__ bo1, const float* __restrict__ bo2, const float* __restrict__ bo3,
    float* __restrict__ out)
{
    __shared__ float sT[4][16*68];
    int tid = threadIdx.x; int w = tid >> 6; int l = tid & 63;
    int quad = l >> 4, col = l & 15;
    int g = blockIdx.x*4 + w;
    int ts = g / 96; int rem = g % 96; int b = rem / 6, it = rem % 6;
    float* sm = sT[w];

    if (ts < 11) {
        const float* hsrc = hall + (size_t)(ts + 1)*HSLOT + (b*NN + it*16)*64;
        int i = l >> 2, c0 = (l & 3)*16;
        #pragma unroll
        for (int cc = 0; cc < 4; cc++)
            *(floatx4*)&sm[i*68 + c0 + cc*4] = *(const floatx4*)&hsrc[i*64 + c0 + cc*4];
    } else {
        // final GRU: reduce 8 partials into sm, gates, elementwise vs h(11)
        int i = l >> 2, c0 = (l & 3)*16;
        floatx4 a[4]; zero4(a);
        for (int p = 0; p < JSPLIT; p++) {
            const float* base = &partial[((p*BSZ + b)*NN + it*16 + i)*64 + c0];
            #pragma unroll
            for (int cc = 0; cc < 4; cc++) a[cc] += *(const floatx4*)&base[cc*4];
        }
        #pragma unroll
        for (int cc = 0; cc < 4; cc++) *(floatx4*)&sm[i*68 + c0 + cc*4] = a[cc];

        short8 a0, a1; buildA(sm, col, quad, a0, a1);
        floatx4 Ar[4], Ai[4], Ah[4];
        zero4(Ar); zero4(Ai); zero4(Ah);
        mm16(a0, a1, (const short8*)wswz + 1*512, l, Ar);
        mm16(a0, a1, (const short8*)wswz + 2*512, l, Ai);
        mm16(a0, a1, (const short8*)wswz + 3*512, l, Ah);
        int s = skills[b*13 + 11];
        const float* hp = hall + 11*(size_t)HSLOT;
        #pragma unroll
        for (int nt = 0; nt < 4; nt++) {
            int d = nt*16 + col;
            float er = Ef[0*6144 + s*64 + d];
            float ei = Ef[1*6144 + s*64 + d];
            float en = Ef[2*6144 + s*64 + d];
            #pragma unroll
            for (int r = 0; r < 4; r++) {
                int row = it*16 + quad*4 + r;
                float gr = fast_sigmoid(er + Ar[nt][r]);
                float gi = fast_sigmoid(ei + Ai[nt][r]);
                float nv = fast_tanh  (en + gr*Ah[nt][r]);
                sm[(quad*4 + r)*68 + d] = (1.f - gi)*nv + gi*hp[(b*NN + row)*64 + d];
            }
        }
    }

    float bv1[4], bv2[4], bv3[4];
    #pragma unroll
    for (int nt = 0; nt < 4; nt++) {
        bv1[nt] = bo1[nt*16 + col];
        bv2[nt] = bo2[nt*16 + col];
        bv3[nt] = bo3[nt*16 + col];
    }
    short8 a0, a1;
    floatx4 acc[4];

    buildA(sm, col, quad, a0, a1);
    zero4(acc);
    mm16(a0, a1, (const short8*)wswz + 6*512, l, acc);
    #pragma unroll
    for (int nt = 0; nt < 4; nt++)
      #pragma unroll
      for (int r = 0; r < 4; r++)
        sm[(quad*4 + r)*68 + nt*16 + col] = fmaxf(0.f, acc[nt][r] + bv1[nt]);

    buildA(sm, col, quad, a0, a1);
    zero4(acc);
    mm16(a0, a1, (const short8*)wswz + 7*512, l, acc);
    #pragma unroll
    for (int nt = 0; nt < 4; nt++)
      #pragma unroll
      for (int r = 0; r < 4; r++)
        sm[(quad*4 + r)*68 + nt*16 + col] = fmaxf(0.f, acc[nt][r] + bv2[nt]);

    buildA(sm, col, quad, a0, a1);
    zero4(acc);
    mm16(a0, a1, (const short8*)wswz + 8*512, l, acc);
    #pragma unroll
    for (int nt = 0; nt < 4; nt++)
      #pragma unroll
      for (int r = 0; r < 4; r++)
        out[((b*TSTEP + ts)*NN + it*16 + quad*4 + r)*64 + nt*16 + col] = acc[nt][r] + bv3[nt];
}

extern "C" void kernel_launch(void* const* d_in, const int* in_sizes, int n_in,
                              void* d_out, int out_size, void* d_ws, size_t ws_size,
                              hipStream_t stream) {
    const int*   skills = (const int*)d_in[0];
    const float* adj    = (const float*)d_in[1];
    const float* emb    = (const float*)d_in[2];
    const float* Wmsg1  = (const float*)d_in[3];
    const float* b1     = (const float*)d_in[4];
    const float* Wmsg2  = (const float*)d_in[5];
    const float* b2     = (const float*)d_in[6];
    const float* Whr    = (const float*)d_in[7];
    const float* Whi    = (const float*)d_in[8];
    const float* Whh    = (const float*)d_in[9];
    const float* Wir    = (const float*)d_in[10];
    const float* bir    = (const float*)d_in[11];
    const float* Wii    = (const float*)d_in[12];
    const float* bii    = (const float*)d_in[13];
    const float* Win    = (const float*)d_in[14];
    const float* bin    = (const float*)d_in[15];
    const float* Wo1    = (const float*)d_in[16];
    const float* bo1    = (const float*)d_in[17];
    const float* Wo2    = (const float*)d_in[18];
    const float* bo2    = (const float*)d_in[19];
    const float* Wo3    = (const float*)d_in[20];
    const float* bo3    = (const float*)d_in[21];

    char* ws = (char*)d_ws;
    float*    hall = (float*)(ws + OFF_HALL);
    float*    Ef   = (float*)(ws + OFF_E);
    float*    S0   = (float*)(ws + OFF_S0);
    float*    R0   = (float*)(ws + OFF_R0);
    float*    S1   = (float*)(ws + OFF_S1);
    float*    R1   = (float*)(ws + OFF_R1);
    float*    P0   = (float*)(ws + OFF_P0);
    float*    P1   = (float*)(ws + OFF_P1);
    ushort_t* wswz = (ushort_t*)(ws + OFF_WSWZ);
    int*      cnt  = (int*)(ws + OFF_CNT);
    int*      flagv= (int*)(ws + OFF_FLAG);
    float*    out  = (float*)d_out;

    k_init<<<dim3(312), dim3(256), 0, stream>>>(emb, Wmsg1, Wmsg2, Whr, Whi, Whh,
        Wir, bir, Wii, bii, Win, bin, Wo1, Wo2, Wo3, hall, cnt, Ef, wswz);

    for (int k = 0; k < 6; k++) {
        k_step2<<<dim3(JSPLIT*BSZ*ITILES), dim3(256), 0, stream>>>(
            adj, b1, b2, skills, Ef, wswz, P0, P1,
            S0, R0, S0, R0, S1, R1, hall, cnt, flagv, k);
    }
    k_out<<<dim3(288), dim3(256), 0, stream>>>(skills, P1, Ef, hall, wswz,
        bo1, bo2, bo3, out);
}